// Round 7
// baseline (3948.090 us; speedup 1.0000x reference)
//
#include <hip/hip_runtime.h>
#include <hip/hip_bf16.h>
#include <math.h>

// Problem constants (match reference)
constexpr int kD = 1024;
constexpr int kH = 16;
constexpr int kDH = 64;     // head dim
constexpr int kV = 32000;
constexpr int kL = 8;
constexpr int kB = 2;
constexpr int kT = 1024;
constexpr int kRows = kB * kT;          // 2048 token rows
constexpr float kEPS = 1e-5f;

typedef unsigned short u16;
typedef __attribute__((ext_vector_type(8))) short short8v;  // 8 bf16 (4 VGPR)
typedef __attribute__((ext_vector_type(4))) float f32x4;

// fp32 -> bf16 (round-to-nearest-even), packed pair into one dword
__device__ __forceinline__ uint32_t pk2(float a, float b) {
    union { float f; uint32_t u; } x, y;
    x.f = a; y.f = b;
    uint32_t lo = (x.u + 0x7FFFu + ((x.u >> 16) & 1)) >> 16;
    uint32_t hi = (y.u + 0x7FFFu + ((y.u >> 16) & 1)) >> 16;
    return lo | (hi << 16);
}
__device__ __forceinline__ u16 bf1(float a) {
    union { float f; uint32_t u; } x; x.f = a;
    return (u16)((x.u + 0x7FFFu + ((x.u >> 16) & 1)) >> 16);
}

// Swizzled 16B-slot index for k-major LDS tiles
__device__ __forceinline__ int swz(int idx, int kg) {
    return idx * 4 + (kg ^ ((idx ^ (idx >> 2)) & 3));
}

// ---------------------------------------------------------------------------
// Embedding
// ---------------------------------------------------------------------------
__global__ __launch_bounds__(256) void embed_kernel(
    const int* __restrict__ tokens, const float* __restrict__ emb,
    const float* __restrict__ pos, float* __restrict__ x)
{
    int row = blockIdx.x;
    int t = row % kT;
    int tok = tokens[row];
    const float4* e = (const float4*)(emb + (size_t)tok * kD);
    const float4* p = (const float4*)(pos + (size_t)t * kD);
    float4* o = (float4*)(x + (size_t)row * kD);
    int i = threadIdx.x;
    float4 a = e[i], b4 = p[i];
    o[i] = make_float4(a.x + b4.x, a.y + b4.y, a.z + b4.z, a.w + b4.w);
}

// ---------------------------------------------------------------------------
// Weight transpose-convert: fp32 [K][N] (+z*K*N) -> bf16 [N][K] (+z*N*K)
// 64x64 tiles via LDS, fully coalesced both sides.
// ---------------------------------------------------------------------------
__global__ __launch_bounds__(256) void wconv_kernel(
    const float* __restrict__ inp, u16* __restrict__ outp, int K, int N)
{
    __shared__ float tile[64][65];
    int k0 = blockIdx.x * 64;
    int n0 = blockIdx.y * 64;
    size_t zin = (size_t)blockIdx.z * (size_t)K * N;
    size_t zout = (size_t)blockIdx.z * (size_t)N * K;
    int tr = threadIdx.x >> 4;              // 0..15
    int tc = (threadIdx.x & 15) * 4;        // 0..60
    #pragma unroll
    for (int i = 0; i < 4; ++i) {
        int r = tr + i * 16;
        float4 f = *(const float4*)(inp + zin + (size_t)(k0 + r) * N + n0 + tc);
        tile[r][tc + 0] = f.x; tile[r][tc + 1] = f.y;
        tile[r][tc + 2] = f.z; tile[r][tc + 3] = f.w;
    }
    __syncthreads();
    #pragma unroll
    for (int i = 0; i < 4; ++i) {
        int n = tr + i * 16;
        uint2 w;
        w.x = pk2(tile[tc + 0][n], tile[tc + 1][n]);
        w.y = pk2(tile[tc + 2][n], tile[tc + 3][n]);
        *(uint2*)(outp + zout + (size_t)(n0 + n) * K + k0 + tc) = w;
    }
}

// ---------------------------------------------------------------------------
// LayerNorm: one block per row. OUTB: write bf16 (u16) or fp32.
// ---------------------------------------------------------------------------
template<bool OUTB>
__global__ __launch_bounds__(256) void ln_kernel(
    const float* __restrict__ x, const float* __restrict__ sc,
    const float* __restrict__ bi, void* __restrict__ outv)
{
    int row = blockIdx.x;
    int tid = threadIdx.x;
    float4 v4 = ((const float4*)(x + (size_t)row * kD))[tid];

    __shared__ float red1[4];
    __shared__ float red2[4];

    float s = v4.x + v4.y + v4.z + v4.w;
    #pragma unroll
    for (int off = 32; off > 0; off >>= 1) s += __shfl_down(s, off);
    if ((tid & 63) == 0) red1[tid >> 6] = s;
    __syncthreads();
    float mean = (red1[0] + red1[1] + red1[2] + red1[3]) * (1.0f / kD);

    float dx = v4.x - mean, dy = v4.y - mean, dz = v4.z - mean, dw = v4.w - mean;
    float vs = dx * dx + dy * dy + dz * dz + dw * dw;
    #pragma unroll
    for (int off = 32; off > 0; off >>= 1) vs += __shfl_down(vs, off);
    if ((tid & 63) == 0) red2[tid >> 6] = vs;
    __syncthreads();
    float var = (red2[0] + red2[1] + red2[2] + red2[3]) * (1.0f / kD);
    float inv = rsqrtf(var + kEPS);

    float4 s4 = ((const float4*)sc)[tid];
    float4 b4 = ((const float4*)bi)[tid];
    float ox = dx * inv * s4.x + b4.x;
    float oy = dy * inv * s4.y + b4.y;
    float oz = dz * inv * s4.z + b4.z;
    float ow = dw * inv * s4.w + b4.w;
    if constexpr (OUTB) {
        uint2 w; w.x = pk2(ox, oy); w.y = pk2(oz, ow);
        ((uint2*)((u16*)outv + (size_t)row * kD))[tid] = w;
    } else {
        ((float4*)((float*)outv + (size_t)row * kD))[tid] = make_float4(ox, oy, oz, ow);
    }
}

// ---------------------------------------------------------------------------
// bf16 MFMA GEMM. INB: A is bf16 [M][K], W is bf16 [N][K] (pre-transposed) —
// staging is pure uint4 copies. !INB: fp32 [M][K] A, fp32 [K][N] W with
// on-the-fly RNE conversion (round-6 path). OUTB: C bf16 vs fp32.
// EPI: 0 = bias, 1 = bias + residual(fp32), 2 = bias + exact GELU
// ---------------------------------------------------------------------------
template<int BM, int BN, int EPI, bool INB, bool OUTB>
__device__ __forceinline__ void mgemm_body(
    const void* __restrict__ Av, const void* __restrict__ Wv_,
    const float* __restrict__ bias, const float* __restrict__ res,
    void* __restrict__ Cv, int N, int K, int bm, int bn)
{
    constexpr int KSTEP = 32;
    constexpr int FM = (BM / 2) / 16;
    constexpr int FN = (BN / 2) / 16;

    __shared__ uint4 smem[BM * 4 + BN * 4];
    char* sA = (char*)smem;
    char* sB = (char*)(smem + BM * 4);

    int tid = threadIdx.x;
    int lane = tid & 63;
    int wv = tid >> 6;
    int wr = wv >> 1, wc = wv & 1;
    int fr = lane & 15;
    int kg = lane >> 4;

    f32x4 acc[FM][FN] = {};

    auto compute = [&]() {
        short8v af[FM], bf[FN];
        #pragma unroll
        for (int mi = 0; mi < FM; ++mi) {
            int row = wr * (BM / 2) + mi * 16 + fr;
            af[mi] = *(const short8v*)(sA + swz(row, kg) * 16);
        }
        #pragma unroll
        for (int nj = 0; nj < FN; ++nj) {
            int col = wc * (BN / 2) + nj * 16 + fr;
            bf[nj] = *(const short8v*)(sB + swz(col, kg) * 16);
        }
        #pragma unroll
        for (int mi = 0; mi < FM; ++mi)
            #pragma unroll
            for (int nj = 0; nj < FN; ++nj)
                acc[mi][nj] = __builtin_amdgcn_mfma_f32_16x16x32_bf16(
                    af[mi], bf[nj], acc[mi][nj], 0, 0, 0);
    };

    if constexpr (INB) {
        const u16* A = (const u16*)Av;          // [M][K] bf16
        const u16* Wt = (const u16*)Wv_;        // [N][K] bf16
        constexpr int A_PER = (BM * 4) / 256;
        constexpr int B_PER = (BN * 4) / 256;
        uint4 pa[A_PER], pb[B_PER];
        auto loadAB = [&](int k0) {
            #pragma unroll
            for (int s = 0; s < A_PER; ++s) {
                int slot = tid * A_PER + s;
                int row = slot >> 2, k8 = slot & 3;
                pa[s] = *(const uint4*)(A + (size_t)(bm + row) * K + k0 + k8 * 8);
            }
            #pragma unroll
            for (int s = 0; s < B_PER; ++s) {
                int slot = tid * B_PER + s;
                int col = slot >> 2, kc = slot & 3;
                pb[s] = *(const uint4*)(Wt + (size_t)(bn + col) * K + k0 + kc * 8);
            }
        };
        auto writeAB = [&]() {
            #pragma unroll
            for (int s = 0; s < A_PER; ++s) {
                int slot = tid * A_PER + s;
                int row = slot >> 2, k8 = slot & 3;
                *(uint4*)(sA + swz(row, k8) * 16) = pa[s];
            }
            #pragma unroll
            for (int s = 0; s < B_PER; ++s) {
                int slot = tid * B_PER + s;
                int col = slot >> 2, kc = slot & 3;
                *(uint4*)(sB + swz(col, kc) * 16) = pb[s];
            }
        };
        loadAB(0); writeAB();
        __syncthreads();
        for (int k0 = 0; k0 < K; k0 += KSTEP) {
            bool more = (k0 + KSTEP) < K;
            if (more) loadAB(k0 + KSTEP);
            compute();
            __syncthreads();
            if (more) {
                writeAB();
                __syncthreads();
            }
        }
    } else {
        const float* A = (const float*)Av;      // [M][K] fp32
        const float* W = (const float*)Wv_;     // [K][N] fp32
        constexpr int A_PER = (BM * 4) / 256;
        constexpr int KPT = BN / 32;
        constexpr int NMASK = BN / 4 - 1;
        constexpr int KQSH = (BN == 128) ? 5 : 4;
        int n4 = tid & NMASK;
        int kq = tid >> KQSH;
        int kbase = kq * KPT;
        float4 pa[A_PER][2];
        float4 pb[KPT];
        auto loadA = [&](int k0) {
            #pragma unroll
            for (int s = 0; s < A_PER; ++s) {
                int slot = tid * A_PER + s;
                int row = slot >> 2, k8 = slot & 3;
                const float* p = A + (size_t)(bm + row) * K + k0 + k8 * 8;
                pa[s][0] = *(const float4*)p;
                pa[s][1] = *(const float4*)(p + 4);
            }
        };
        auto loadB = [&](int k0) {
            #pragma unroll
            for (int i = 0; i < KPT; ++i)
                pb[i] = *(const float4*)(W + (size_t)(k0 + kbase + i) * N + bn + n4 * 4);
        };
        auto writeA = [&]() {
            #pragma unroll
            for (int s = 0; s < A_PER; ++s) {
                int slot = tid * A_PER + s;
                int row = slot >> 2, k8 = slot & 3;
                uint4 w;
                w.x = pk2(pa[s][0].x, pa[s][0].y);
                w.y = pk2(pa[s][0].z, pa[s][0].w);
                w.z = pk2(pa[s][1].x, pa[s][1].y);
                w.w = pk2(pa[s][1].z, pa[s][1].w);
                *(uint4*)(sA + swz(row, k8) * 16) = w;
            }
        };
        auto writeB = [&]() {
            int kgc = kbase >> 3;
            int kb8 = (kbase & 7) * 2;
            #pragma unroll
            for (int j = 0; j < 4; ++j) {
                int col = n4 * 4 + j;
                char* dst = sB + swz(col, kgc) * 16 + kb8;
                if constexpr (KPT == 4) {
                    uint2 w;
                    w.x = pk2((&pb[0].x)[j], (&pb[1].x)[j]);
                    w.y = pk2((&pb[2].x)[j], (&pb[3].x)[j]);
                    *(uint2*)dst = w;
                } else {
                    *(uint32_t*)dst = pk2((&pb[0].x)[j], (&pb[1].x)[j]);
                }
            }
        };
        loadA(0); loadB(0);
        writeA(); writeB();
        __syncthreads();
        for (int k0 = 0; k0 < K; k0 += KSTEP) {
            bool more = (k0 + KSTEP) < K;
            if (more) { loadA(k0 + KSTEP); loadB(k0 + KSTEP); }
            compute();
            __syncthreads();
            if (more) {
                writeA(); writeB();
                __syncthreads();
            }
        }
    }

    // ---- epilogue ----
    #pragma unroll
    for (int mi = 0; mi < FM; ++mi) {
        #pragma unroll
        for (int nj = 0; nj < FN; ++nj) {
            int col = bn + wc * (BN / 2) + nj * 16 + fr;
            float bia = bias[col];
            #pragma unroll
            for (int r = 0; r < 4; ++r) {
                int row = bm + wr * (BM / 2) + mi * 16 + kg * 4 + r;
                float o = acc[mi][nj][r] + bia;
                if (EPI == 1) o += res[(size_t)row * N + col];
                if (EPI == 2) o = 0.5f * o * (1.0f + erff(o * 0.70710678118f));
                if constexpr (OUTB)
                    ((u16*)Cv)[(size_t)row * N + col] = bf1(o);
                else
                    ((float*)Cv)[(size_t)row * N + col] = o;
            }
        }
    }
}

template<int BM, int BN, int EPI, bool INB, bool OUTB>
__global__ __launch_bounds__(256) void mgemm_kernel(
    const void* __restrict__ A, const void* __restrict__ W,
    const float* __restrict__ bias, const float* __restrict__ res,
    void* __restrict__ C, int N, int K)
{
    mgemm_body<BM, BN, EPI, INB, OUTB>(A, W, bias, res, C, N, K,
                                       blockIdx.x * BM, blockIdx.y * BN);
}

// QKV: blockIdx.z selects {q,k,v}
template<bool FAST>
__global__ __launch_bounds__(256) void qkv_kernel(
    const void* __restrict__ A,
    const void* __restrict__ W0, const float* __restrict__ b0, void* __restrict__ C0,
    const void* __restrict__ W1, const float* __restrict__ b1, void* __restrict__ C1,
    const void* __restrict__ W2, const float* __restrict__ b2, void* __restrict__ C2)
{
    const void* W = (blockIdx.z == 0) ? W0 : (blockIdx.z == 1) ? W1 : W2;
    const float* b = (blockIdx.z == 0) ? b0 : (blockIdx.z == 1) ? b1 : b2;
    void* C        = (blockIdx.z == 0) ? C0 : (blockIdx.z == 1) ? C1 : C2;
    mgemm_body<128, 64, 0, FAST, FAST>(A, W, b, nullptr, C, kD, kD,
                                       blockIdx.x * 128, blockIdx.y * 64);
}

// ---------------------------------------------------------------------------
// Flash attention, bf16 MFMA. B16: q/k/v/y are bf16; else fp32 (round-6 path).
// Block = 4 waves, 64 q-rows; KV tiles of 64; swizzled LDS.
// ---------------------------------------------------------------------------
template<bool B16>
__global__ __launch_bounds__(256) void fattn_kernel(
    const void* __restrict__ qv, const void* __restrict__ kv,
    const void* __restrict__ vv, void* __restrict__ yv)
{
    int qt = (int)(gridDim.x - 1) - (int)blockIdx.x;   // reversed: big first
    int h = blockIdx.y;
    int b = blockIdx.z;
    int q0 = qt * 64;

    __shared__ __align__(16) char sQ[8192];    // [64 q ][8 dg]
    __shared__ __align__(16) char sK[8192];    // [64 k ][8 dg]
    __shared__ __align__(16) char sVT[8192];   // [64 d ][8 kg]
    __shared__ __align__(16) char sP[4][2048]; // per-wave [16 q][8 kg]

    int tid = threadIdx.x;
    int lane = tid & 63;
    int w = tid >> 6;
    int fr = lane & 15;
    int g4 = lane >> 4;

    int srow = tid >> 2;
    int c4 = tid & 3;

    // ---- stage Q tile ----
    if constexpr (B16) {
        const u16* src = (const u16*)qv + (size_t)(b * kT + q0 + srow) * kD + h * kDH + c4 * 16;
        uint4 w0 = ((const uint4*)src)[0];
        uint4 w1 = ((const uint4*)src)[1];
        *(uint4*)(sQ + srow * 128 + (((c4 * 2)     ^ (srow & 7)) * 16)) = w0;
        *(uint4*)(sQ + srow * 128 + (((c4 * 2 + 1) ^ (srow & 7)) * 16)) = w1;
    } else {
        const float* src = (const float*)qv + (size_t)(b * kT + q0 + srow) * kD + h * kDH + c4 * 16;
        float4 f0 = ((const float4*)src)[0];
        float4 f1 = ((const float4*)src)[1];
        float4 f2 = ((const float4*)src)[2];
        float4 f3 = ((const float4*)src)[3];
        const float s8 = 0.125f;
        uint4 w0, w1;
        w0.x = pk2(f0.x * s8, f0.y * s8); w0.y = pk2(f0.z * s8, f0.w * s8);
        w0.z = pk2(f1.x * s8, f1.y * s8); w0.w = pk2(f1.z * s8, f1.w * s8);
        w1.x = pk2(f2.x * s8, f2.y * s8); w1.y = pk2(f2.z * s8, f2.w * s8);
        w1.z = pk2(f3.x * s8, f3.y * s8); w1.w = pk2(f3.z * s8, f3.w * s8);
        *(uint4*)(sQ + srow * 128 + (((c4 * 2)     ^ (srow & 7)) * 16)) = w0;
        *(uint4*)(sQ + srow * 128 + (((c4 * 2 + 1) ^ (srow & 7)) * 16)) = w1;
    }
    __syncthreads();

    short8v aq[2];
    {
        int row = w * 16 + fr;
        aq[0] = *(const short8v*)(sQ + row * 128 + (((g4)     ^ (fr & 7)) * 16));
        aq[1] = *(const short8v*)(sQ + row * 128 + (((4 + g4) ^ (fr & 7)) * 16));
    }

    f32x4 accO[4] = {};
    float mrow[4], lrow[4];
    #pragma unroll
    for (int r = 0; r < 4; ++r) { mrow[r] = -INFINITY; lrow[r] = 0.0f; }

    int ntiles = qt + 1;
    for (int t = 0; t < ntiles; ++t) {
        int k0 = t * 64;
        __syncthreads();
        // ---- stage K tile ----
        if constexpr (B16) {
            const u16* src = (const u16*)kv + (size_t)(b * kT + k0 + srow) * kD + h * kDH + c4 * 16;
            uint4 w0 = ((const uint4*)src)[0];
            uint4 w1 = ((const uint4*)src)[1];
            *(uint4*)(sK + srow * 128 + (((c4 * 2)     ^ (srow & 7)) * 16)) = w0;
            *(uint4*)(sK + srow * 128 + (((c4 * 2 + 1) ^ (srow & 7)) * 16)) = w1;
        } else {
            const float* src = (const float*)kv + (size_t)(b * kT + k0 + srow) * kD + h * kDH + c4 * 16;
            float4 f0 = ((const float4*)src)[0];
            float4 f1 = ((const float4*)src)[1];
            float4 f2 = ((const float4*)src)[2];
            float4 f3 = ((const float4*)src)[3];
            uint4 w0, w1;
            w0.x = pk2(f0.x, f0.y); w0.y = pk2(f0.z, f0.w);
            w0.z = pk2(f1.x, f1.y); w0.w = pk2(f1.z, f1.w);
            w1.x = pk2(f2.x, f2.y); w1.y = pk2(f2.z, f2.w);
            w1.z = pk2(f3.x, f3.y); w1.w = pk2(f3.z, f3.w);
            *(uint4*)(sK + srow * 128 + (((c4 * 2)     ^ (srow & 7)) * 16)) = w0;
            *(uint4*)(sK + srow * 128 + (((c4 * 2 + 1) ^ (srow & 7)) * 16)) = w1;
        }
        // ---- stage V^T tile ----
        {
            int kg = srow >> 3;
            int kb2 = (srow & 7) * 2;
            if constexpr (B16) {
                const u16* src = (const u16*)vv + (size_t)(b * kT + k0 + srow) * kD + h * kDH + c4 * 16;
                u16 vals[16];
                *(uint4*)(vals) = ((const uint4*)src)[0];
                *(uint4*)(vals + 8) = ((const uint4*)src)[1];
                #pragma unroll
                for (int j = 0; j < 16; ++j) {
                    int d = c4 * 16 + j;
                    *(u16*)(sVT + d * 128 + ((kg ^ (d & 7)) * 16) + kb2) = vals[j];
                }
            } else {
                const float* src = (const float*)vv + (size_t)(b * kT + k0 + srow) * kD + h * kDH + c4 * 16;
                #pragma unroll
                for (int j = 0; j < 4; ++j) {
                    float4 f = ((const float4*)src)[j];
                    int dbase = c4 * 16 + j * 4;
                    *(u16*)(sVT + (dbase + 0) * 128 + ((kg ^ ((dbase + 0) & 7)) * 16) + kb2) = bf1(f.x);
                    *(u16*)(sVT + (dbase + 1) * 128 + ((kg ^ ((dbase + 1) & 7)) * 16) + kb2) = bf1(f.y);
                    *(u16*)(sVT + (dbase + 2) * 128 + ((kg ^ ((dbase + 2) & 7)) * 16) + kb2) = bf1(f.z);
                    *(u16*)(sVT + (dbase + 3) * 128 + ((kg ^ ((dbase + 3) & 7)) * 16) + kb2) = bf1(f.w);
                }
            }
        }
        __syncthreads();

        // ---- S = Q K^T ----
        f32x4 s[4];
        #pragma unroll
        for (int nj = 0; nj < 4; ++nj) { s[nj][0] = 0; s[nj][1] = 0; s[nj][2] = 0; s[nj][3] = 0; }
        #pragma unroll
        for (int nj = 0; nj < 4; ++nj) {
            int krow = nj * 16 + fr;
            short8v bk0 = *(const short8v*)(sK + krow * 128 + (((g4)     ^ (fr & 7)) * 16));
            short8v bk1 = *(const short8v*)(sK + krow * 128 + (((4 + g4) ^ (fr & 7)) * 16));
            s[nj] = __builtin_amdgcn_mfma_f32_16x16x32_bf16(aq[0], bk0, s[nj], 0, 0, 0);
            s[nj] = __builtin_amdgcn_mfma_f32_16x16x32_bf16(aq[1], bk1, s[nj], 0, 0, 0);
        }
        if constexpr (B16) {   // post-scale by 1/sqrt(64) (exact pow2)
            #pragma unroll
            for (int nj = 0; nj < 4; ++nj)
                #pragma unroll
                for (int r = 0; r < 4; ++r) s[nj][r] *= 0.125f;
        }

        // ---- causal mask on diagonal tile ----
        if (t == qt) {
            #pragma unroll
            for (int nj = 0; nj < 4; ++nj)
                #pragma unroll
                for (int r = 0; r < 4; ++r) {
                    int qq = w * 16 + g4 * 4 + r;
                    int kk = nj * 16 + fr;
                    if (kk > qq) s[nj][r] = -1e30f;
                }
        }

        // ---- online softmax ----
        float tm[4];
        #pragma unroll
        for (int r = 0; r < 4; ++r)
            tm[r] = fmaxf(fmaxf(s[0][r], s[1][r]), fmaxf(s[2][r], s[3][r]));
        #pragma unroll
        for (int mk = 1; mk <= 8; mk <<= 1)
            #pragma unroll
            for (int r = 0; r < 4; ++r)
                tm[r] = fmaxf(tm[r], __shfl_xor(tm[r], mk));

        float scl[4];
        #pragma unroll
        for (int r = 0; r < 4; ++r) {
            float mnew = fmaxf(mrow[r], tm[r]);
            scl[r] = __expf(mrow[r] - mnew);
            mrow[r] = mnew;
        }
        float ps[4][4];
        float psum[4];
        #pragma unroll
        for (int r = 0; r < 4; ++r) {
            ps[0][r] = __expf(s[0][r] - mrow[r]);
            ps[1][r] = __expf(s[1][r] - mrow[r]);
            ps[2][r] = __expf(s[2][r] - mrow[r]);
            ps[3][r] = __expf(s[3][r] - mrow[r]);
            psum[r] = ps[0][r] + ps[1][r] + ps[2][r] + ps[3][r];
        }
        #pragma unroll
        for (int mk = 1; mk <= 8; mk <<= 1)
            #pragma unroll
            for (int r = 0; r < 4; ++r)
                psum[r] += __shfl_xor(psum[r], mk);
        #pragma unroll
        for (int r = 0; r < 4; ++r)
            lrow[r] = lrow[r] * scl[r] + psum[r];
        #pragma unroll
        for (int nj = 0; nj < 4; ++nj)
            #pragma unroll
            for (int r = 0; r < 4; ++r)
                accO[nj][r] *= scl[r];

        // ---- P -> per-wave LDS (bf16), PV via MFMA ----
        #pragma unroll
        for (int nj = 0; nj < 4; ++nj) {
            int kg = nj * 2 + (fr >> 3);
            #pragma unroll
            for (int r = 0; r < 4; ++r) {
                int qq = g4 * 4 + r;
                *(u16*)(sP[w] + qq * 128 + ((kg ^ (qq & 7)) * 16) + (fr & 7) * 2) = bf1(ps[nj][r]);
            }
        }
        #pragma unroll
        for (int ks = 0; ks < 2; ++ks) {
            short8v ap = *(const short8v*)(sP[w] + fr * 128 + (((ks * 4 + g4) ^ (fr & 7)) * 16));
            #pragma unroll
            for (int nj = 0; nj < 4; ++nj) {
                int drow = nj * 16 + fr;
                short8v bv_ = *(const short8v*)(sVT + drow * 128 + (((ks * 4 + g4) ^ (fr & 7)) * 16));
                accO[nj] = __builtin_amdgcn_mfma_f32_16x16x32_bf16(ap, bv_, accO[nj], 0, 0, 0);
            }
        }
    }

    // ---- epilogue ----
    float invl[4];
    #pragma unroll
    for (int r = 0; r < 4; ++r) invl[r] = 1.0f / lrow[r];
    #pragma unroll
    for (int nj = 0; nj < 4; ++nj) {
        #pragma unroll
        for (int r = 0; r < 4; ++r) {
            int qg = q0 + w * 16 + g4 * 4 + r;
            int d = nj * 16 + fr;
            float o = accO[nj][r] * invl[r];
            if constexpr (B16)
                ((u16*)yv)[(size_t)(b * kT + qg) * kD + h * kDH + d] = bf1(o);
            else
                ((float*)yv)[(size_t)(b * kT + qg) * kD + h * kDH + d] = o;
        }
    }
}

// ---------------------------------------------------------------------------
// Host-side launch
// ---------------------------------------------------------------------------
extern "C" void kernel_launch(void* const* d_in, const int* in_sizes, int n_in,
                              void* d_out, int out_size, void* d_ws, size_t ws_size,
                              hipStream_t stream)
{
    const int*   tokens = (const int*)  d_in[0];
    const float* emb    = (const float*)d_in[1];
    const float* pos    = (const float*)d_in[2];
    const float* ln1_s  = (const float*)d_in[3];
    const float* ln1_b  = (const float*)d_in[4];
    const float* Wq     = (const float*)d_in[5];
    const float* bq     = (const float*)d_in[6];
    const float* Wk     = (const float*)d_in[7];
    const float* bk     = (const float*)d_in[8];
    const float* Wv     = (const float*)d_in[9];
    const float* bv     = (const float*)d_in[10];
    const float* Wo     = (const float*)d_in[11];
    const float* bo     = (const float*)d_in[12];
    const float* ln2_s  = (const float*)d_in[13];
    const float* ln2_b  = (const float*)d_in[14];
    const float* W1     = (const float*)d_in[15];
    const float* b1     = (const float*)d_in[16];
    const float* W2     = (const float*)d_in[17];
    const float* b2     = (const float*)d_in[18];
    const float* lnf_s  = (const float*)d_in[19];
    const float* lnf_b  = (const float*)d_in[20];
    const float* Wl     = (const float*)d_in[21];
    const float* bl     = (const float*)d_in[22];
    float* out = (float*)d_out;

    size_t BTD = (size_t)kRows * kD;     // 2,097,152
    size_t DD  = (size_t)kD * kD;        // 1,048,576

    // ---- fast-path workspace layout ----
    float* x    = (float*)d_ws;          // fp32 residual, 8 MB
    u16* h16    = (u16*)(x + BTD);       // 4 MB
    u16* qb16   = h16 + BTD;
    u16* kb16   = qb16 + BTD;
    u16* vb16   = kb16 + BTD;
    u16* mid16  = vb16 + BTD;            // 16 MB
    u16* wqt    = mid16 + 4 * BTD;
    u16* wkt    = wqt + (size_t)kL * DD;
    u16* wvt    = wkt + (size_t)kL * DD;
    u16* wot    = wvt + (size_t)kL * DD;
    u16* w1t    = wot + (size_t)kL * DD;
    u16* w2t    = w1t + (size_t)kL * 4 * DD;
    u16* wlt    = w2t + (size_t)kL * 4 * DD;
    u16* wend   = wlt + (size_t)kV * kD;
    size_t need = (size_t)((char*)wend - (char*)d_ws);
    bool fast = ws_size >= need;

    dim3 gAttn(kT / 64, kH, kB);

    if (fast) {
        // one-time (per launch) weight transpose-convert to bf16 [N][K]
        wconv_kernel<<<dim3(16, 16, kL), 256, 0, stream>>>(Wq, wqt, kD, kD);
        wconv_kernel<<<dim3(16, 16, kL), 256, 0, stream>>>(Wk, wkt, kD, kD);
        wconv_kernel<<<dim3(16, 16, kL), 256, 0, stream>>>(Wv, wvt, kD, kD);
        wconv_kernel<<<dim3(16, 16, kL), 256, 0, stream>>>(Wo, wot, kD, kD);
        wconv_kernel<<<dim3(16, 64, kL), 256, 0, stream>>>(W1, w1t, kD, 4 * kD);
        wconv_kernel<<<dim3(64, 16, kL), 256, 0, stream>>>(W2, w2t, 4 * kD, kD);
        wconv_kernel<<<dim3(16, 500, 1), 256, 0, stream>>>(Wl, wlt, kD, kV);

        embed_kernel<<<kRows, 256, 0, stream>>>(tokens, emb, pos, x);

        for (int i = 0; i < kL; ++i) {
            size_t oD  = (size_t)i * kD;
            size_t oD4 = (size_t)i * 4 * kD;

            ln_kernel<true><<<kRows, 256, 0, stream>>>(x, ln1_s + oD, ln1_b + oD, h16);

            qkv_kernel<true><<<dim3(16, 16, 3), 256, 0, stream>>>(h16,
                wqt + i * DD, bq + oD, qb16,
                wkt + i * DD, bk + oD, kb16,
                wvt + i * DD, bv + oD, vb16);

            fattn_kernel<true><<<gAttn, 256, 0, stream>>>(qb16, kb16, vb16, h16);

            mgemm_kernel<128, 64, 1, true, false><<<dim3(16, 16), 256, 0, stream>>>(
                h16, wot + i * DD, bo + oD, x, x, kD, kD);

            ln_kernel<true><<<kRows, 256, 0, stream>>>(x, ln2_s + oD, ln2_b + oD, h16);

            mgemm_kernel<128, 128, 2, true, true><<<dim3(16, 32), 256, 0, stream>>>(
                h16, w1t + i * 4 * DD, b1 + oD4, nullptr, mid16, 4 * kD, kD);
            mgemm_kernel<128, 64, 1, true, false><<<dim3(16, 16), 256, 0, stream>>>(
                mid16, w2t + i * 4 * DD, b2 + oD, x, x, kD, 4 * kD);
        }

        ln_kernel<true><<<kRows, 256, 0, stream>>>(x, lnf_s, lnf_b, h16);
        mgemm_kernel<128, 128, 0, true, false><<<dim3(16, 250), 256, 0, stream>>>(
            h16, wlt, bl, nullptr, out, kV, kD);
    } else {
        // fallback = validated round-6 path (fp32 buffers, on-the-fly convert)
        float* h   = x + BTD;
        float* qb  = h + BTD;
        float* kb  = qb + BTD;
        float* vb  = kb + BTD;
        float* mid = qb;                 // aliases qb..vb (dead after attn)

        embed_kernel<<<kRows, 256, 0, stream>>>(tokens, emb, pos, x);

        for (int i = 0; i < kL; ++i) {
            size_t oD  = (size_t)i * kD;
            size_t oDD = (size_t)i * DD;
            size_t oD4 = (size_t)i * 4 * kD;
            size_t oDD4 = (size_t)i * 4 * DD;

            ln_kernel<false><<<kRows, 256, 0, stream>>>(x, ln1_s + oD, ln1_b + oD, h);

            qkv_kernel<false><<<dim3(16, 16, 3), 256, 0, stream>>>(h,
                Wq + oDD, bq + oD, qb,
                Wk + oDD, bk + oD, kb,
                Wv + oDD, bv + oD, vb);

            fattn_kernel<false><<<gAttn, 256, 0, stream>>>(qb, kb, vb, h);

            mgemm_kernel<128, 64, 1, false, false><<<dim3(16, 16), 256, 0, stream>>>(
                h, Wo + oDD, bo + oD, x, x, kD, kD);

            ln_kernel<false><<<kRows, 256, 0, stream>>>(x, ln2_s + oD, ln2_b + oD, h);

            mgemm_kernel<128, 128, 2, false, false><<<dim3(16, 32), 256, 0, stream>>>(
                h, W1 + oDD4, b1 + oD4, nullptr, mid, 4 * kD, kD);
            mgemm_kernel<128, 64, 1, false, false><<<dim3(16, 16), 256, 0, stream>>>(
                mid, W2 + oDD4, b2 + oD, x, x, kD, 4 * kD);
        }

        ln_kernel<false><<<kRows, 256, 0, stream>>>(x, lnf_s, lnf_b, h);
        mgemm_kernel<128, 128, 0, false, false><<<dim3(16, 250), 256, 0, stream>>>(
            h, Wl, bl, nullptr, out, kV, kD);
    }
}